// Round 1
// baseline (1305.803 us; speedup 1.0000x reference)
//
#include <hip/hip_runtime.h>

// ---------------- constants ----------------
#define LOG_DELTA (-5.2983174f)   // ln(0.005)

// ws layout (float offsets)
constexpr size_t OFF_C1G1  = 0;                       // [12][32][50]
constexpr size_t OFF_C1G2  = 19200;                   // [12][32][50]
constexpr size_t OFF_ACCS  = 38400;                   // [16]
constexpr size_t OFF_C0G   = 38416;                   // [12][7000][50]
constexpr size_t OFF_BETA  = OFF_C0G  + 4200000;      // [600][7000]
constexpr size_t OFF_ALPHAT= OFF_BETA + 4200000;      // [600][300]
constexpr size_t OFF_INP   = OFF_ALPHAT + 180000;     // [384][400]
constexpr size_t OFF_X0    = OFF_INP  + 153600;       // [384][1600]
constexpr size_t OFF_OUT0  = OFF_X0   + 614400;       // [384][400]
constexpr size_t OFF_X1    = OFF_OUT0 + 153600;       // [384][1600]
constexpr size_t OFF_OUT1  = OFF_X1   + 614400;       // [384][400]
constexpr size_t OFF_CST   = OFF_OUT1 + 153600;       // [32][400]
constexpr size_t OFF_MUH   = OFF_CST  + 12800;        // [384][50]
constexpr size_t OFF_LSH   = OFF_MUH  + 19200;        // [384][50]
constexpr size_t OFF_THETA = OFF_LSH  + 19200;        // [12][32][50]
constexpr size_t OFF_LTH   = OFF_THETA+ 19200;        // [12][32][50]
constexpr size_t OFF_MUW4  = OFF_LTH  + 19200;        // [50][400]
constexpr size_t OFF_LSW4  = OFF_MUW4 + 20000;        // [50][400]
constexpr size_t OFF_ZSG   = OFF_LSW4 + 20000;        // [12][32][50]

// ---------------- helpers ----------------
__device__ __forceinline__ float wsum64(float x){
  #pragma unroll
  for (int o = 32; o; o >>= 1) x += __shfl_down(x, o);
  return x;
}
__device__ __forceinline__ float wmax64(float x){
  #pragma unroll
  for (int o = 32; o; o >>= 1) x = fmaxf(x, __shfl_down(x, o));
  return x;
}
// lowbias32 hash -> uniform (0,1)
__device__ __forceinline__ float u01(unsigned int x){
  x ^= x >> 16; x *= 0x7feb352dU;
  x ^= x >> 15; x *= 0x846ca68bU;
  x ^= x >> 16;
  return ((float)x + 0.5f) * (1.0f/4294967296.0f);
}

// ---------------- trivial kernels ----------------
__global__ void zero_f32(float* __restrict__ p, int n){
  for (int i = blockIdx.x*blockDim.x + threadIdx.x; i < n; i += gridDim.x*blockDim.x) p[i] = 0.f;
}
// pack [50][450] -> [50][400] (cols 0..399)
__global__ void pack_w450(const float* __restrict__ w, float* __restrict__ o){
  for (int i = blockIdx.x*blockDim.x + threadIdx.x; i < 20000; i += gridDim.x*blockDim.x){
    int k = i / 400, j = i % 400;
    o[i] = w[k*450 + j];
  }
}
// alphaT[(t*50+k)*300 + r] = mu_q_alpha[(k*12+t)*300 + r]
__global__ void alpha_tr(const float* __restrict__ mu, float* __restrict__ o){
  for (int i = blockIdx.x*blockDim.x + threadIdx.x; i < 180000; i += gridDim.x*blockDim.x){
    int m = i / 300, r = i % 300;
    int t = m / 50, k = m % 50;
    o[i] = mu[((size_t)k*12 + t)*300 + r];
  }
}
// C[m][n] = b1[n] (+ b2[n])
__global__ void set_bias(float* __restrict__ C, int ldc, int M, int N,
                         const float* __restrict__ b1, const float* __restrict__ b2){
  int total = M*N;
  for (int i = blockIdx.x*blockDim.x + threadIdx.x; i < total; i += gridDim.x*blockDim.x){
    int m = i / N, n = i % N;
    float v = b1 ? b1[n] : 0.f;
    if (b2) v += b2[n];
    C[(size_t)m*ldc + n] = v;
  }
}

// ---------------- GEMM: C += A[M,K] * B[N,K]^T (split-K, atomic) ----------------
__device__ __forceinline__ float4 g4(const float* __restrict__ base, int row, int nrows,
                                     int ld, int k, int kend){
  float4 v; v.x = v.y = v.z = v.w = 0.f;
  if (row < nrows){
    const float* q = base + (size_t)row*ld + k;
    if (k + 3 < kend) v = *(const float4*)q;
    else {
      if (k   < kend) v.x = q[0];
      if (k+1 < kend) v.y = q[1];
      if (k+2 < kend) v.z = q[2];
      if (k+3 < kend) v.w = q[3];
    }
  }
  return v;
}

__global__ __launch_bounds__(256) void gemm_f32(
    const float* __restrict__ A, int lda,
    const float* __restrict__ B, int ldb,
    float* __restrict__ C, int ldc,
    int M, int N, int K, int kchunk)
{
  __shared__ __align__(16) float As[16][68];
  __shared__ __align__(16) float Bs[16][68];
  const int tid = threadIdx.x;
  const int m0 = blockIdx.y * 64, n0 = blockIdx.x * 64;
  const int kbeg = blockIdx.z * kchunk;
  const int kend = min(K, kbeg + kchunk);
  const int lm  = tid >> 2;
  const int lkq = (tid & 3) << 2;
  const int ty = tid >> 4, tx = tid & 15;
  float acc[4][4];
  #pragma unroll
  for (int i=0;i<4;++i)
    #pragma unroll
    for (int j=0;j<4;++j) acc[i][j] = 0.f;

  for (int k0 = kbeg; k0 < kend; k0 += 16){
    float4 av = g4(A, m0+lm, M, lda, k0+lkq, kend);
    float4 bv = g4(B, n0+lm, N, ldb, k0+lkq, kend);
    As[lkq+0][lm]=av.x; As[lkq+1][lm]=av.y; As[lkq+2][lm]=av.z; As[lkq+3][lm]=av.w;
    Bs[lkq+0][lm]=bv.x; Bs[lkq+1][lm]=bv.y; Bs[lkq+2][lm]=bv.z; Bs[lkq+3][lm]=bv.w;
    __syncthreads();
    #pragma unroll
    for (int kk = 0; kk < 16; ++kk){
      const float4 a = *(const float4*)&As[kk][ty<<2];
      const float4 b = *(const float4*)&Bs[kk][tx<<2];
      float ar[4] = {a.x,a.y,a.z,a.w};
      float br[4] = {b.x,b.y,b.z,b.w};
      #pragma unroll
      for (int i=0;i<4;++i)
        #pragma unroll
        for (int j=0;j<4;++j) acc[i][j] = fmaf(ar[i], br[j], acc[i][j]);
    }
    __syncthreads();
  }
  const int om = m0 + (ty<<2), on = n0 + (tx<<2);
  #pragma unroll
  for (int i=0;i<4;++i)
    #pragma unroll
    for (int j=0;j<4;++j)
      if (om+i < M && on+j < N)
        atomicAdd(&C[(size_t)(om+i)*ldc + (on+j)], acc[i][j]);
}

// ---------------- LSTM step ----------------
// grid 50 blocks x 256; block owns u-tile of 8 (all 32 b, 4 gates)
__global__ __launch_bounds__(256) void lstm_step(
    const float* __restrict__ X,    // [384][1600], row b*12+t
    const float* __restrict__ whh,  // [1600][400]
    float* __restrict__ hs,         // [384][400], row b*12+t
    float* __restrict__ cst,        // [32][400]
    int t)
{
  __shared__ float h_s[32][105];
  __shared__ float w_s[32][105];
  __shared__ float red[4][32][33];
  const int tid = threadIdx.x;
  const int u0 = blockIdx.x * 8;
  const int wv = tid >> 6, lane = tid & 63;
  const int bg = lane & 7;       // b rows: bg + 8*i
  const int jg = lane >> 3;      // j rows: jg + 8*j

  float acc[4][4];
  #pragma unroll
  for (int i=0;i<4;++i)
    #pragma unroll
    for (int j=0;j<4;++j) acc[i][j] = 0.f;

  for (int kc = 0; kc < 4; ++kc){
    const int r0 = kc * 100;
    for (int lin = tid; lin < 3200; lin += 256){
      int b = lin / 100, r = lin % 100;
      h_s[b][r] = (t == 0) ? 0.f : hs[((size_t)b*12 + (t-1))*400 + r0 + r];
    }
    for (int lin = tid; lin < 3200; lin += 256){
      int j = lin / 100, r = lin % 100;
      w_s[j][r] = whh[((size_t)((j>>3)*400 + u0 + (j&7)))*400 + r0 + r];
    }
    __syncthreads();
    const int rb = wv * 25;
    for (int rr = rb; rr < rb + 25; ++rr){
      float a0 = h_s[bg+ 0][rr], a1 = h_s[bg+ 8][rr], a2 = h_s[bg+16][rr], a3 = h_s[bg+24][rr];
      float w0 = w_s[jg+ 0][rr], w1 = w_s[jg+ 8][rr], w2 = w_s[jg+16][rr], w3 = w_s[jg+24][rr];
      acc[0][0] = fmaf(a0,w0,acc[0][0]); acc[0][1] = fmaf(a0,w1,acc[0][1]);
      acc[0][2] = fmaf(a0,w2,acc[0][2]); acc[0][3] = fmaf(a0,w3,acc[0][3]);
      acc[1][0] = fmaf(a1,w0,acc[1][0]); acc[1][1] = fmaf(a1,w1,acc[1][1]);
      acc[1][2] = fmaf(a1,w2,acc[1][2]); acc[1][3] = fmaf(a1,w3,acc[1][3]);
      acc[2][0] = fmaf(a2,w0,acc[2][0]); acc[2][1] = fmaf(a2,w1,acc[2][1]);
      acc[2][2] = fmaf(a2,w2,acc[2][2]); acc[2][3] = fmaf(a2,w3,acc[2][3]);
      acc[3][0] = fmaf(a3,w0,acc[3][0]); acc[3][1] = fmaf(a3,w1,acc[3][1]);
      acc[3][2] = fmaf(a3,w2,acc[3][2]); acc[3][3] = fmaf(a3,w3,acc[3][3]);
    }
    __syncthreads();
  }
  #pragma unroll
  for (int i=0;i<4;++i)
    #pragma unroll
    for (int j=0;j<4;++j) red[wv][bg + 8*i][jg + 8*j] = acc[i][j];
  __syncthreads();

  // gate phase: thread -> (b, ul)
  {
    const int b = tid >> 3, ul = tid & 7;
    float gs[4];
    #pragma unroll
    for (int g = 0; g < 4; ++g){
      float s = X[((size_t)b*12 + t)*1600 + g*400 + u0 + ul];
      #pragma unroll
      for (int w = 0; w < 4; ++w) s += red[w][b][g*8 + ul];
      gs[g] = s;
    }
    float ii = 1.f/(1.f + expf(-gs[0]));
    float ff = 1.f/(1.f + expf(-gs[1]));
    float gg = tanhf(gs[2]);
    float oo = 1.f/(1.f + expf(-gs[3]));
    float c = (t == 0) ? 0.f : cst[b*400 + u0 + ul];
    c = ff*c + ii*gg;
    float h = oo * tanhf(c);
    cst[b*400 + u0 + ul] = c;
    hs[((size_t)b*12 + t)*400 + u0 + ul] = h;
  }
}

// ---------------- theta head (single block, sequential over t) ----------------
__global__ __launch_bounds__(512) void theta_seq(
    const float* __restrict__ muH, const float* __restrict__ lsH,  // [384][50], row b*12+t
    const float* __restrict__ muW, const float* __restrict__ lsW,  // [50][450]
    float* __restrict__ theta, float* __restrict__ ltheta,         // [12][32][50]
    float* __restrict__ zsg,                                       // [12][32][50]
    float* __restrict__ accs)
{
  __shared__ float zsl[2][32][50];
  __shared__ float wm[50][51], wl[50][51];
  __shared__ float ktot;
  const int tid = threadIdx.x;
  for (int i = tid; i < 2500; i += 512){
    int k = i / 50, j = i % 50;
    wm[k][j] = muW[k*450 + 400 + j];
    wl[k][j] = lsW[k*450 + 400 + j];
  }
  if (tid == 0) ktot = 0.f;
  __syncthreads();
  const float dd = expf(LOG_DELTA) + 1e-6f;
  for (int t = 0; t < 12; ++t){
    float kpart = 0.f;
    for (int idx = tid; idx < 1600; idx += 512){
      int b = idx / 50, k = idx % 50;
      float m = muH[((size_t)b*12 + t)*50 + k];
      float l = lsH[((size_t)b*12 + t)*50 + k];
      float zp = 0.f;
      if (t > 0){
        zp = zsl[(t-1)&1][b][k];
        float sm = 0.f, sl = 0.f;
        #pragma unroll 5
        for (int j = 0; j < 50; ++j){
          float z = zsl[(t-1)&1][b][j];
          sm = fmaf(z, wm[k][j], sm);
          sl = fmaf(z, wl[k][j], sl);
        }
        m += sm; l += sl;
      }
      zsl[t&1][b][k] = m;
      zsg[((size_t)t*32 + b)*50 + k] = m;
      float denom = (t > 0) ? dd : (1.f + 1e-6f);
      float pls = (t > 0) ? LOG_DELTA : 0.f;
      float d = m - zp;
      kpart += (expf(l) + d*d)/denom - 1.f + pls - l;
    }
    kpart = wsum64(kpart);
    if ((tid & 63) == 0) atomicAdd(&ktot, 0.5f * kpart / 32.f);
    __syncthreads();
  }
  // theta = softmax_k(zs), ltheta = log(theta)
  for (int row = tid; row < 384; row += 512){
    float m = -3.0e38f;
    for (int k = 0; k < 50; ++k) m = fmaxf(m, zsg[(size_t)row*50 + k]);
    float S = 0.f;
    for (int k = 0; k < 50; ++k) S += expf(zsg[(size_t)row*50 + k] - m);
    float lS = logf(S), inv = 1.f/S;
    for (int k = 0; k < 50; ++k){
      float z = zsg[(size_t)row*50 + k];
      theta[(size_t)row*50 + k]  = expf(z - m) * inv;
      ltheta[(size_t)row*50 + k] = (z - m) - lS;
    }
  }
  if (tid == 0) atomicAdd(&accs[6], ktot);
}

// ---------------- kld_alpha ----------------
__global__ void kld_alpha_k(const float* __restrict__ qmu, const float* __restrict__ qls,
                            float* __restrict__ accs){
  const int t = blockIdx.x / 50, k = blockIdx.x % 50;
  const size_t base  = ((size_t)k*12 + t)*300;
  const size_t pbase = ((size_t)k*12 + (t-1))*300;
  const float dd  = (t > 0) ? (expf(LOG_DELTA) + 1e-6f) : (1.f + 1e-6f);
  const float pls = (t > 0) ? LOG_DELTA : 0.f;
  float s = 0.f;
  for (int r = threadIdx.x; r < 300; r += 64){
    float qm = qmu[base + r], ql = qls[base + r];
    float pm = (t > 0) ? qmu[pbase + r] : 0.f;
    float d = qm - pm;
    s += (expf(ql) + d*d)/dd - 1.f + pls - ql;
  }
  s = wsum64(s);
  if (threadIdx.x == 0) atomicAdd(&accs[7], 0.5f * s / 50.f);
}

// ---------------- row softmax over vocab segment (in place) ----------------
__global__ __launch_bounds__(256) void softmax_seg(float* __restrict__ buf){
  const int row = blockIdx.x, part = blockIdx.y;
  float* p = buf + (size_t)row*7000 + (part ? 5000 : 0);
  const int n = part ? 2000 : 5000;
  __shared__ float sred[8];
  const int tid = threadIdx.x;
  float m = -3.0e38f;
  for (int i = tid; i < n; i += 256) m = fmaxf(m, p[i]);
  m = wmax64(m);
  if ((tid & 63) == 0) sred[tid >> 6] = m;
  __syncthreads();
  m = fmaxf(fmaxf(sred[0], sred[1]), fmaxf(sred[2], sred[3]));
  float s = 0.f;
  for (int i = tid; i < n; i += 256) s += __expf(p[i] - m);
  s = wsum64(s);
  if ((tid & 63) == 0) sred[4 + (tid >> 6)] = s;
  __syncthreads();
  s = sred[4] + sred[5] + sred[6] + sred[7];
  const float inv = 1.f/s;
  for (int i = tid; i < n; i += 256) p[i] = __expf(p[i] - m) * inv;
}

// ---------------- pass1: sample z, counts + kld_z terms ----------------
__global__ __launch_bounds__(256) void pass1(
    const float* __restrict__ beta,   // [600][7000]
    const float* __restrict__ theta,  // [12][32][50]
    const float* __restrict__ ltheta,
    float* __restrict__ c0g,          // [12][7000][50]
    float* __restrict__ c1g1, float* __restrict__ c1g2,  // [12][32][50]
    float* __restrict__ accs)
{
  const int t = blockIdx.y;
  const int v0 = blockIdx.x * 64;
  __shared__ float th[32][50], lth[32][50];
  __shared__ float be[50][64];
  __shared__ float c0s[64][50];
  __shared__ float c1s[2][32][50];
  __shared__ float kred[4];
  const int tid = threadIdx.x;
  for (int i = tid; i < 1600; i += 256){
    th[i/50][i%50]  = theta [(size_t)t*1600 + i];
    lth[i/50][i%50] = ltheta[(size_t)t*1600 + i];
  }
  for (int i = tid; i < 3200; i += 256){
    int k = i >> 6, vl = i & 63, v = v0 + vl;
    be[k][vl] = (v < 7000) ? beta[((size_t)t*50 + k)*7000 + v] : 0.f;
  }
  for (int i = tid; i < 3200; i += 256) ((float*)c0s)[i] = 0.f;
  for (int i = tid; i < 3200; i += 256) ((float*)c1s)[i] = 0.f;
  if (tid < 4) kred[tid] = 0.f;
  __syncthreads();

  const int b = tid >> 3, sub = tid & 7;
  float kA1 = 0.f, kB1 = 0.f, kA2 = 0.f, kB2 = 0.f;
  float e[50], f[50];
  for (int it = 0; it < 8; ++it){
    const int vl = sub + (it << 3);
    const int v = v0 + vl;
    if (v < 7000){
      float m1 = -3.0e38f;
      #pragma unroll
      for (int k = 0; k < 50; ++k){ float s = th[b][k]*be[k][vl]; e[k] = s; m1 = fmaxf(m1, s); }
      float S1 = 0.f;
      #pragma unroll
      for (int k = 0; k < 50; ++k){ float ee = __expf(e[k] - m1); e[k] = ee; S1 += ee; }
      const float inv = 1.f/S1;
      float F = 0.f;
      #pragma unroll
      for (int k = 0; k < 50; ++k){ float fk = __expf(e[k]*inv); f[k] = fk; F += fk; }
      const unsigned int seed = (unsigned int)(((t*32) + b)*7000 + v);
      const float rthr = u01(seed) * F;
      float csum = 0.f; int ks = 49; float pis = e[49]*inv; bool found = false;
      #pragma unroll
      for (int k = 0; k < 50; ++k){
        csum += f[k];
        if (!found && csum >= rthr){ ks = k; pis = e[k]*inv; found = true; }
      }
      const float lpis = __logf(pis);
      const float lt = lth[b][ks];
      if (v >= 5000){ kA2 += lt; kB2 += pis*lpis; }
      else          { kA1 += lt; kB1 += pis*lpis; }
      atomicAdd(&c0s[vl][ks], 1.f);
      atomicAdd(&c1s[(v >= 5000) ? 1 : 0][b][ks], 1.f);
    }
  }
  kA1 = wsum64(kA1); kB1 = wsum64(kB1); kA2 = wsum64(kA2); kB2 = wsum64(kB2);
  if ((tid & 63) == 0){
    atomicAdd(&kred[0], kA1); atomicAdd(&kred[1], kB1);
    atomicAdd(&kred[2], kA2); atomicAdd(&kred[3], kB2);
  }
  __syncthreads();
  for (int i = tid; i < 3200; i += 256){
    int vl = i / 50, k = i % 50, v = v0 + vl;
    if (v < 7000) c0g[((size_t)t*7000 + v)*50 + k] = c0s[vl][k];
  }
  for (int i = tid; i < 1600; i += 256){
    float x1 = ((float*)c1s)[i];
    float x2 = ((float*)c1s)[1600 + i];
    if (x1 != 0.f) atomicAdd(&c1g1[(size_t)t*1600 + i], x1);
    if (x2 != 0.f) atomicAdd(&c1g2[(size_t)t*1600 + i], x2);
  }
  if (tid < 4) atomicAdd(&accs[tid], kred[tid]);
}

// ---------------- pass2: log-likelihood ----------------
__global__ __launch_bounds__(256) void pass2(
    const float* __restrict__ beta, const float* __restrict__ theta,
    const float* __restrict__ c0g,
    const float* __restrict__ c1g1, const float* __restrict__ c1g2,
    const float* __restrict__ bows, float* __restrict__ accs)
{
  const int t = blockIdx.y, v0 = blockIdx.x * 64;
  __shared__ float be[50][64];
  __shared__ __align__(16) float tz[2][32][52];
  __shared__ __align__(16) float bz[64][52];
  __shared__ float sr[2];
  const int tid = threadIdx.x;
  if (tid < 2) sr[tid] = 0.f;
  for (int i = tid; i < 3200; i += 256){
    int k = i >> 6, vl = i & 63, v = v0 + vl;
    be[k][vl] = (v < 7000) ? beta[((size_t)t*50 + k)*7000 + v] : 0.f;
  }
  for (int i = tid; i < 1600; i += 256){
    int b = i / 50, k = i % 50;
    float th_ = theta[(size_t)t*1600 + i];
    tz[0][b][k] = th_ * c1g1[(size_t)t*1600 + i] * (1.f/5000.f);
    tz[1][b][k] = th_ * c1g2[(size_t)t*1600 + i] * (1.f/2000.f);
  }
  for (int i = tid; i < 128; i += 256){
    int b = i >> 2, rem = i & 3, p = rem >> 1, j = 50 + (rem & 1);
    tz[p][b][j] = 0.f;
  }
  __syncthreads();
  for (int i = tid; i < 3200; i += 256){
    int vl = i / 50, k = i % 50, v = v0 + vl;
    bz[vl][k] = (v < 7000) ? be[k][vl] * c0g[((size_t)t*7000 + v)*50 + k] * (1.f/32.f) : 0.f;
  }
  for (int i = tid; i < 128; i += 256){ int vl = i >> 1; bz[vl][50 + (i & 1)] = 0.f; }
  __syncthreads();

  const int b = tid >> 3, sub = tid & 7;
  float s1 = 0.f, s2 = 0.f;
  for (int it = 0; it < 8; ++it){
    const int vl = sub + (it << 3);
    const int v = v0 + vl;
    if (v < 7000){
      const int p = (v >= 5000);
      float dot = 0.f;
      #pragma unroll
      for (int kq = 0; kq < 13; ++kq){
        const float4 a = *(const float4*)&tz[p][b][kq << 2];
        const float4 c = *(const float4*)&bz[vl][kq << 2];
        dot += a.x*c.x + a.y*c.y + a.z*c.z + a.w*c.w;
      }
      const float w = bows[((size_t)b*12 + t)*7000 + v];
      const float l = __logf(dot) * w;
      if (p) s2 += l; else s1 += l;
    }
  }
  s1 = wsum64(s1); s2 = wsum64(s2);
  if ((tid & 63) == 0){ atomicAdd(&sr[0], s1); atomicAdd(&sr[1], s2); }
  __syncthreads();
  if (tid < 2) atomicAdd(&accs[4 + tid], sr[tid]);
}

// ---------------- finalize ----------------
__global__ void finalize_k(const float* __restrict__ accs, float* __restrict__ out){
  if (threadIdx.x == 0 && blockIdx.x == 0){
    out[0] = -(accs[4] + accs[5]) * (1.f/32.f);           // recon_loss = -ll1 - ll2
    out[1] = accs[6];                                     // kld_theta
    out[2] = -accs[0]/(32.f*5000.f) - accs[1]/32.f;       // kld_z1
    out[3] = -accs[2]/(32.f*2000.f) - accs[3]/32.f;       // kld_z2
    out[4] = accs[7];                                     // kld_alpha
  }
}

// ---------------- host launcher ----------------
extern "C" void kernel_launch(void* const* d_in, const int* in_sizes, int n_in,
                              void* d_out, int out_size, void* d_ws, size_t ws_size,
                              hipStream_t stream)
{
  const float* bows   = (const float*)d_in[0];
  const float* nbows  = (const float*)d_in[1];
  const float* qmap_w = (const float*)d_in[2];
  const float* qmap_b = (const float*)d_in[3];
  const float* wih0   = (const float*)d_in[4];
  const float* whh0   = (const float*)d_in[5];
  const float* bih0   = (const float*)d_in[6];
  const float* bhh0   = (const float*)d_in[7];
  const float* wih1   = (const float*)d_in[8];
  const float* whh1   = (const float*)d_in[9];
  const float* bih1   = (const float*)d_in[10];
  const float* bhh1   = (const float*)d_in[11];
  const float* muW    = (const float*)d_in[12];
  const float* muB    = (const float*)d_in[13];
  const float* lsW    = (const float*)d_in[14];
  const float* lsB    = (const float*)d_in[15];
  const float* qmu    = (const float*)d_in[16];
  const float* qlsa   = (const float*)d_in[17];
  const float* rho1w  = (const float*)d_in[18];
  const float* rho1b  = (const float*)d_in[19];
  const float* rho2w  = (const float*)d_in[20];
  const float* rho2b  = (const float*)d_in[21];

  float* ws  = (float*)d_ws;
  float* out = (float*)d_out;

  float* c1g1  = ws + OFF_C1G1;
  float* c1g2  = ws + OFF_C1G2;
  float* accs  = ws + OFF_ACCS;
  float* c0g   = ws + OFF_C0G;
  float* beta  = ws + OFF_BETA;
  float* alphT = ws + OFF_ALPHAT;
  float* inp   = ws + OFF_INP;
  float* X0    = ws + OFF_X0;
  float* out0  = ws + OFF_OUT0;
  float* X1    = ws + OFF_X1;
  float* out1  = ws + OFF_OUT1;
  float* cst   = ws + OFF_CST;
  float* muH   = ws + OFF_MUH;
  float* lsH   = ws + OFF_LSH;
  float* theta = ws + OFF_THETA;
  float* lth   = ws + OFF_LTH;
  float* muW4  = ws + OFF_MUW4;
  float* lsW4  = ws + OFF_LSW4;
  float* zsg   = ws + OFF_ZSG;

  // zero the atomically-accumulated buffers (c1g1, c1g2, accs contiguous)
  zero_f32<<<152, 256, 0, stream>>>(c1g1, 38416);
  pack_w450<<<79, 256, 0, stream>>>(muW, muW4);
  pack_w450<<<79, 256, 0, stream>>>(lsW, lsW4);
  alpha_tr<<<704, 256, 0, stream>>>(qmu, alphT);
  kld_alpha_k<<<600, 64, 0, stream>>>(qmu, qlsa, accs);

  // inp = nbows @ qmap_w^T + qmap_b   [384,400], K=7000
  set_bias<<<600, 256, 0, stream>>>(inp, 400, 384, 400, qmap_b, nullptr);
  gemm_f32<<<dim3(7,6,6), 256, 0, stream>>>(nbows, 7000, qmap_w, 7000, inp, 400, 384, 400, 7000, 1168);

  // X0 = inp @ wih0^T + bih0 + bhh0   [384,1600], K=400
  set_bias<<<2048, 256, 0, stream>>>(X0, 1600, 384, 1600, bih0, bhh0);
  gemm_f32<<<dim3(25,6,2), 256, 0, stream>>>(inp, 400, wih0, 400, X0, 1600, 384, 1600, 400, 208);
  for (int t = 0; t < 12; ++t)
    lstm_step<<<50, 256, 0, stream>>>(X0, whh0, out0, cst, t);

  // X1 = out0 @ wih1^T + bih1 + bhh1
  set_bias<<<2048, 256, 0, stream>>>(X1, 1600, 384, 1600, bih1, bhh1);
  gemm_f32<<<dim3(25,6,2), 256, 0, stream>>>(out0, 400, wih1, 400, X1, 1600, 384, 1600, 400, 208);
  for (int t = 0; t < 12; ++t)
    lstm_step<<<50, 256, 0, stream>>>(X1, whh1, out1, cst, t);

  // muH/lsH = out1 @ W[:, :400]^T + b   [384,50], K=400
  set_bias<<<75, 256, 0, stream>>>(muH, 50, 384, 50, muB, nullptr);
  gemm_f32<<<dim3(1,6,2), 256, 0, stream>>>(out1, 400, muW4, 400, muH, 50, 384, 50, 400, 208);
  set_bias<<<75, 256, 0, stream>>>(lsH, 50, 384, 50, lsB, nullptr);
  gemm_f32<<<dim3(1,6,2), 256, 0, stream>>>(out1, 400, lsW4, 400, lsH, 50, 384, 50, 400, 208);

  theta_seq<<<1, 512, 0, stream>>>(muH, lsH, muW, lsW, theta, lth, zsg, accs);

  // beta logits: [600, 7000] = alphaT @ rho^T + rho_b, then row-softmax per part
  set_bias<<<2048, 256, 0, stream>>>(beta, 7000, 600, 5000, rho1b, nullptr);
  gemm_f32<<<dim3(79,10,1), 256, 0, stream>>>(alphT, 300, rho1w, 300, beta, 7000, 600, 5000, 300, 304);
  set_bias<<<2048, 256, 0, stream>>>(beta + 5000, 7000, 600, 2000, rho2b, nullptr);
  gemm_f32<<<dim3(32,10,1), 256, 0, stream>>>(alphT, 300, rho2w, 300, beta + 5000, 7000, 600, 2000, 300, 304);
  softmax_seg<<<dim3(600,2), 256, 0, stream>>>(beta);

  // likelihood
  pass1<<<dim3(110,12), 256, 0, stream>>>(beta, theta, lth, c0g, c1g1, c1g2, accs);
  pass2<<<dim3(110,12), 256, 0, stream>>>(beta, theta, c0g, c1g1, c1g2, bows, accs);

  finalize_k<<<1, 64, 0, stream>>>(accs, out);
}

// Round 2
// 1091.111 us; speedup vs baseline: 1.1968x; 1.1968x over previous
//
#include <hip/hip_runtime.h>

// ---------------- constants ----------------
#define LOG_DELTA (-5.2983174f)   // ln(0.005)

// ws layout (float offsets)
constexpr size_t OFF_C1G1  = 0;                       // [12][32][50]
constexpr size_t OFF_C1G2  = 19200;                   // [12][32][50]
constexpr size_t OFF_ACCS  = 38400;                   // [16]
constexpr size_t OFF_C0G   = 38416;                   // [12][7000][50]
constexpr size_t OFF_BETA  = OFF_C0G  + 4200000;      // [600][7000]
constexpr size_t OFF_ALPHAT= OFF_BETA + 4200000;      // [600][300]
constexpr size_t OFF_INP   = OFF_ALPHAT + 180000;     // [384][400]
constexpr size_t OFF_X0    = OFF_INP  + 153600;       // [384][1600]
constexpr size_t OFF_OUT0  = OFF_X0   + 614400;       // [384][400]
constexpr size_t OFF_X1    = OFF_OUT0 + 153600;       // [384][1600]
constexpr size_t OFF_OUT1  = OFF_X1   + 614400;       // [384][400]
constexpr size_t OFF_CST   = OFF_OUT1 + 153600;       // [32][400]
constexpr size_t OFF_MUH   = OFF_CST  + 12800;        // [384][50]
constexpr size_t OFF_LSH   = OFF_MUH  + 19200;        // [384][50]
constexpr size_t OFF_THETA = OFF_LSH  + 19200;        // [12][32][50]
constexpr size_t OFF_LTH   = OFF_THETA+ 19200;        // [12][32][50]
constexpr size_t OFF_MUW4  = OFF_LTH  + 19200;        // [50][400]
constexpr size_t OFF_LSW4  = OFF_MUW4 + 20000;        // [50][400]
constexpr size_t OFF_ZSG   = OFF_LSW4 + 20000;        // [12][32][50]

// ---------------- helpers ----------------
__device__ __forceinline__ float wsum64(float x){
  #pragma unroll
  for (int o = 32; o; o >>= 1) x += __shfl_down(x, o);
  return x;
}
__device__ __forceinline__ float wmax64(float x){
  #pragma unroll
  for (int o = 32; o; o >>= 1) x = fmaxf(x, __shfl_down(x, o));
  return x;
}
// lowbias32 hash -> uniform (0,1)
__device__ __forceinline__ float u01(unsigned int x){
  x ^= x >> 16; x *= 0x7feb352dU;
  x ^= x >> 15; x *= 0x846ca68bU;
  x ^= x >> 16;
  return ((float)x + 0.5f) * (1.0f/4294967296.0f);
}

// ---------------- fused prep: zero accum buffers, pack W450, transpose alpha ----
// ranges: [0,38416) zero c1g1/c1g2/accs; [38416,58416) muW4; [58416,78416) lsW4;
//         [78416,258416) alphaT
__global__ void prep_misc(const float* __restrict__ muW, const float* __restrict__ lsW,
                          const float* __restrict__ qmu,
                          float* __restrict__ zbase, float* __restrict__ muW4,
                          float* __restrict__ lsW4, float* __restrict__ alphT){
  for (int i = blockIdx.x*blockDim.x + threadIdx.x; i < 258416; i += gridDim.x*blockDim.x){
    if (i < 38416) zbase[i] = 0.f;
    else if (i < 58416){ int j = i - 38416; muW4[j] = muW[(j/400)*450 + (j%400)]; }
    else if (i < 78416){ int j = i - 58416; lsW4[j] = lsW[(j/400)*450 + (j%400)]; }
    else {
      int j = i - 78416; int m = j/300, r = j%300; int t = m/50, k = m%50;
      alphT[j] = qmu[((size_t)k*12 + t)*300 + r];
    }
  }
}

// ---------------- fused bias init for all GEMM outputs ----------------
__global__ void bias_all(float* __restrict__ inp, float* __restrict__ X0,
                         float* __restrict__ X1, float* __restrict__ muH,
                         float* __restrict__ lsH,
                         const float* __restrict__ qb,
                         const float* __restrict__ bi0, const float* __restrict__ bh0,
                         const float* __restrict__ bi1, const float* __restrict__ bh1,
                         const float* __restrict__ mb,  const float* __restrict__ lb){
  // 153600 inp | 614400 X0 | 614400 X1 | 19200 muH | 19200 lsH = 1420800
  for (int i = blockIdx.x*blockDim.x + threadIdx.x; i < 1420800; i += gridDim.x*blockDim.x){
    if (i < 153600) inp[i] = qb[i % 400];
    else if (i < 768000){ int j = i - 153600; int n = j % 1600; X0[j] = bi0[n] + bh0[n]; }
    else if (i < 1382400){ int j = i - 768000; int n = j % 1600; X1[j] = bi1[n] + bh1[n]; }
    else if (i < 1401600){ int j = i - 1382400; muH[j] = mb[j % 50]; }
    else { int j = i - 1401600; lsH[j] = lb[j % 50]; }
  }
}

// ---------------- GEMM: C (+)= A[M,K] * B[N,K]^T ----------------
// direct==1: C = acc + bias[n] (requires gridDim.z==1). direct==0: atomicAdd into
// pre-initialized C.
__device__ __forceinline__ float4 g4(const float* __restrict__ base, int row, int nrows,
                                     int ld, int k, int kend){
  float4 v; v.x = v.y = v.z = v.w = 0.f;
  if (row < nrows){
    const float* q = base + (size_t)row*ld + k;
    if (k + 3 < kend) v = *(const float4*)q;
    else {
      if (k   < kend) v.x = q[0];
      if (k+1 < kend) v.y = q[1];
      if (k+2 < kend) v.z = q[2];
      if (k+3 < kend) v.w = q[3];
    }
  }
  return v;
}

__global__ __launch_bounds__(256) void gemm_f32(
    const float* __restrict__ A, int lda,
    const float* __restrict__ B, int ldb,
    float* __restrict__ C, int ldc,
    int M, int N, int K, int kchunk,
    const float* __restrict__ bias, int direct)
{
  __shared__ __align__(16) float As[16][68];
  __shared__ __align__(16) float Bs[16][68];
  const int tid = threadIdx.x;
  const int m0 = blockIdx.y * 64, n0 = blockIdx.x * 64;
  const int kbeg = blockIdx.z * kchunk;
  const int kend = min(K, kbeg + kchunk);
  const int lm  = tid >> 2;
  const int lkq = (tid & 3) << 2;
  const int ty = tid >> 4, tx = tid & 15;
  float acc[4][4];
  #pragma unroll
  for (int i=0;i<4;++i)
    #pragma unroll
    for (int j=0;j<4;++j) acc[i][j] = 0.f;

  for (int k0 = kbeg; k0 < kend; k0 += 16){
    float4 av = g4(A, m0+lm, M, lda, k0+lkq, kend);
    float4 bv = g4(B, n0+lm, N, ldb, k0+lkq, kend);
    As[lkq+0][lm]=av.x; As[lkq+1][lm]=av.y; As[lkq+2][lm]=av.z; As[lkq+3][lm]=av.w;
    Bs[lkq+0][lm]=bv.x; Bs[lkq+1][lm]=bv.y; Bs[lkq+2][lm]=bv.z; Bs[lkq+3][lm]=bv.w;
    __syncthreads();
    #pragma unroll
    for (int kk = 0; kk < 16; ++kk){
      const float4 a = *(const float4*)&As[kk][ty<<2];
      const float4 b = *(const float4*)&Bs[kk][tx<<2];
      float ar[4] = {a.x,a.y,a.z,a.w};
      float br[4] = {b.x,b.y,b.z,b.w};
      #pragma unroll
      for (int i=0;i<4;++i)
        #pragma unroll
        for (int j=0;j<4;++j) acc[i][j] = fmaf(ar[i], br[j], acc[i][j]);
    }
    __syncthreads();
  }
  const int om = m0 + (ty<<2), on = n0 + (tx<<2);
  if (direct){
    #pragma unroll
    for (int i=0;i<4;++i)
      #pragma unroll
      for (int j=0;j<4;++j)
        if (om+i < M && on+j < N)
          C[(size_t)(om+i)*ldc + (on+j)] = acc[i][j] + (bias ? bias[on+j] : 0.f);
  } else {
    #pragma unroll
    for (int i=0;i<4;++i)
      #pragma unroll
      for (int j=0;j<4;++j)
        if (om+i < M && on+j < N)
          atomicAdd(&C[(size_t)(om+i)*ldc + (on+j)], acc[i][j]);
  }
}

// ---------------- LSTM step ----------------
// grid 100 blocks x 256; block owns u-tile of 4 (all 32 b, 4 gates = 16 outputs/b)
__global__ __launch_bounds__(256) void lstm_step(
    const float* __restrict__ X,    // [384][1600], row b*12+t
    const float* __restrict__ whh,  // [1600][400]
    float* __restrict__ hs,         // [384][400], row b*12+t
    float* __restrict__ cst,        // [32][400]
    int t)
{
  __shared__ float h_s[32][105];
  __shared__ float w_s[16][105];
  __shared__ float red[4][32][17];
  const int tid = threadIdx.x;
  const int u0 = blockIdx.x * 4;
  const int wv = tid >> 6, lane = tid & 63;
  const int bg = lane & 7;       // b rows: bg + 8*i
  const int jg = lane >> 3;      // j rows: jg + 8*jj

  float acc[4][2];
  #pragma unroll
  for (int i=0;i<4;++i){ acc[i][0] = 0.f; acc[i][1] = 0.f; }

  for (int kc = 0; kc < 4; ++kc){
    const int r0 = kc * 100;
    for (int lin = tid; lin < 3200; lin += 256){
      int b = lin / 100, r = lin % 100;
      h_s[b][r] = (t == 0) ? 0.f : hs[((size_t)b*12 + (t-1))*400 + r0 + r];
    }
    for (int lin = tid; lin < 1600; lin += 256){
      int j = lin / 100, r = lin % 100;
      w_s[j][r] = whh[((size_t)((j>>2)*400 + u0 + (j&3)))*400 + r0 + r];
    }
    __syncthreads();
    const int rb = wv * 25;
    for (int rr = rb; rr < rb + 25; ++rr){
      float a0 = h_s[bg+ 0][rr], a1 = h_s[bg+ 8][rr], a2 = h_s[bg+16][rr], a3 = h_s[bg+24][rr];
      float w0 = w_s[jg][rr],    w1 = w_s[jg+ 8][rr];
      acc[0][0] = fmaf(a0,w0,acc[0][0]); acc[0][1] = fmaf(a0,w1,acc[0][1]);
      acc[1][0] = fmaf(a1,w0,acc[1][0]); acc[1][1] = fmaf(a1,w1,acc[1][1]);
      acc[2][0] = fmaf(a2,w0,acc[2][0]); acc[2][1] = fmaf(a2,w1,acc[2][1]);
      acc[3][0] = fmaf(a3,w0,acc[3][0]); acc[3][1] = fmaf(a3,w1,acc[3][1]);
    }
    __syncthreads();
  }
  #pragma unroll
  for (int i=0;i<4;++i){
    red[wv][bg + 8*i][jg    ] = acc[i][0];
    red[wv][bg + 8*i][jg + 8] = acc[i][1];
  }
  __syncthreads();

  if (tid < 128){
    const int b = tid >> 2, ul = tid & 3;
    float gs[4];
    #pragma unroll
    for (int g = 0; g < 4; ++g){
      float s = X[((size_t)b*12 + t)*1600 + g*400 + u0 + ul];
      #pragma unroll
      for (int w = 0; w < 4; ++w) s += red[w][b][g*4 + ul];
      gs[g] = s;
    }
    float ii = 1.f/(1.f + expf(-gs[0]));
    float ff = 1.f/(1.f + expf(-gs[1]));
    float gg = tanhf(gs[2]);
    float oo = 1.f/(1.f + expf(-gs[3]));
    float c = (t == 0) ? 0.f : cst[b*400 + u0 + ul];
    c = ff*c + ii*gg;
    float h = oo * tanhf(c);
    cst[b*400 + u0 + ul] = c;
    hs[((size_t)b*12 + t)*400 + u0 + ul] = h;
  }
}

// ---------------- theta head (single block, sequential over t) ----------------
__global__ __launch_bounds__(512) void theta_seq(
    const float* __restrict__ muH, const float* __restrict__ lsH,  // [384][50], row b*12+t
    const float* __restrict__ muW, const float* __restrict__ lsW,  // [50][450]
    float* __restrict__ theta, float* __restrict__ ltheta,         // [12][32][50]
    float* __restrict__ zsg,                                       // [12][32][50]
    float* __restrict__ accs)
{
  __shared__ float zsl[2][32][50];
  __shared__ float wm[50][51], wl[50][51];
  __shared__ float ktot;
  const int tid = threadIdx.x;
  for (int i = tid; i < 2500; i += 512){
    int k = i / 50, j = i % 50;
    wm[k][j] = muW[k*450 + 400 + j];
    wl[k][j] = lsW[k*450 + 400 + j];
  }
  if (tid == 0) ktot = 0.f;
  __syncthreads();
  const float dd = expf(LOG_DELTA) + 1e-6f;
  for (int t = 0; t < 12; ++t){
    float kpart = 0.f;
    for (int idx = tid; idx < 1600; idx += 512){
      int b = idx / 50, k = idx % 50;
      float m = muH[((size_t)b*12 + t)*50 + k];
      float l = lsH[((size_t)b*12 + t)*50 + k];
      float zp = 0.f;
      if (t > 0){
        zp = zsl[(t-1)&1][b][k];
        float sm = 0.f, sl = 0.f;
        #pragma unroll 5
        for (int j = 0; j < 50; ++j){
          float z = zsl[(t-1)&1][b][j];
          sm = fmaf(z, wm[k][j], sm);
          sl = fmaf(z, wl[k][j], sl);
        }
        m += sm; l += sl;
      }
      zsl[t&1][b][k] = m;
      zsg[((size_t)t*32 + b)*50 + k] = m;
      float denom = (t > 0) ? dd : (1.f + 1e-6f);
      float pls = (t > 0) ? LOG_DELTA : 0.f;
      float d = m - zp;
      kpart += (expf(l) + d*d)/denom - 1.f + pls - l;
    }
    kpart = wsum64(kpart);
    if ((tid & 63) == 0) atomicAdd(&ktot, 0.5f * kpart / 32.f);
    __syncthreads();
  }
  // theta = softmax_k(zs), ltheta = log(theta)
  for (int row = tid; row < 384; row += 512){
    float m = -3.0e38f;
    for (int k = 0; k < 50; ++k) m = fmaxf(m, zsg[(size_t)row*50 + k]);
    float S = 0.f;
    for (int k = 0; k < 50; ++k) S += expf(zsg[(size_t)row*50 + k] - m);
    float lS = logf(S), inv = 1.f/S;
    for (int k = 0; k < 50; ++k){
      float z = zsg[(size_t)row*50 + k];
      theta[(size_t)row*50 + k]  = expf(z - m) * inv;
      ltheta[(size_t)row*50 + k] = (z - m) - lS;
    }
  }
  if (tid == 0) atomicAdd(&accs[6], ktot);
}

// ---------------- kld_alpha ----------------
__global__ void kld_alpha_k(const float* __restrict__ qmu, const float* __restrict__ qls,
                            float* __restrict__ accs){
  const int t = blockIdx.x / 50, k = blockIdx.x % 50;
  const size_t base  = ((size_t)k*12 + t)*300;
  const size_t pbase = ((size_t)k*12 + (t-1))*300;
  const float dd  = (t > 0) ? (expf(LOG_DELTA) + 1e-6f) : (1.f + 1e-6f);
  const float pls = (t > 0) ? LOG_DELTA : 0.f;
  float s = 0.f;
  for (int r = threadIdx.x; r < 300; r += 64){
    float qm = qmu[base + r], ql = qls[base + r];
    float pm = (t > 0) ? qmu[pbase + r] : 0.f;
    float d = qm - pm;
    s += (expf(ql) + d*d)/dd - 1.f + pls - ql;
  }
  s = wsum64(s);
  if (threadIdx.x == 0) atomicAdd(&accs[7], 0.5f * s / 50.f);
}

// ---------------- row softmax over vocab segment (in place) ----------------
__global__ __launch_bounds__(256) void softmax_seg(float* __restrict__ buf){
  const int row = blockIdx.x, part = blockIdx.y;
  float* p = buf + (size_t)row*7000 + (part ? 5000 : 0);
  const int n = part ? 2000 : 5000;
  __shared__ float sred[8];
  const int tid = threadIdx.x;
  float m = -3.0e38f;
  for (int i = tid; i < n; i += 256) m = fmaxf(m, p[i]);
  m = wmax64(m);
  if ((tid & 63) == 0) sred[tid >> 6] = m;
  __syncthreads();
  m = fmaxf(fmaxf(sred[0], sred[1]), fmaxf(sred[2], sred[3]));
  float s = 0.f;
  for (int i = tid; i < n; i += 256) s += __expf(p[i] - m);
  s = wsum64(s);
  if ((tid & 63) == 0) sred[4 + (tid >> 6)] = s;
  __syncthreads();
  s = sred[4] + sred[5] + sred[6] + sred[7];
  const float inv = 1.f/s;
  for (int i = tid; i < n; i += 256) p[i] = __expf(p[i] - m) * inv;
}

// ---------------- pass1: sample z, counts + kld_z terms ----------------
// Spill-free: single a[50] register array; e recomputed once for the selected k.
__global__ __launch_bounds__(256) void pass1(
    const float* __restrict__ beta,   // [600][7000]
    const float* __restrict__ theta,  // [12][32][50]
    const float* __restrict__ ltheta,
    float* __restrict__ c0g,          // [12][7000][50]
    float* __restrict__ c1g1, float* __restrict__ c1g2,  // [12][32][50]
    float* __restrict__ accs)
{
  const int t = blockIdx.y;
  const int v0 = blockIdx.x * 64;
  __shared__ float th[32][50], lth[32][50];
  __shared__ float be[50][64];
  __shared__ float c0s[64][50];
  __shared__ float c1s[2][32][50];
  __shared__ float kred[4];
  const int tid = threadIdx.x;
  for (int i = tid; i < 1600; i += 256){
    th[i/50][i%50]  = theta [(size_t)t*1600 + i];
    lth[i/50][i%50] = ltheta[(size_t)t*1600 + i];
  }
  for (int i = tid; i < 3200; i += 256){
    int k = i >> 6, vl = i & 63, v = v0 + vl;
    be[k][vl] = (v < 7000) ? beta[((size_t)t*50 + k)*7000 + v] : 0.f;
  }
  for (int i = tid; i < 3200; i += 256) ((float*)c0s)[i] = 0.f;
  for (int i = tid; i < 3200; i += 256) ((float*)c1s)[i] = 0.f;
  if (tid < 4) kred[tid] = 0.f;
  __syncthreads();

  const int b = tid >> 3, sub = tid & 7;
  float kA1 = 0.f, kB1 = 0.f, kA2 = 0.f, kB2 = 0.f;
  float a[50];
  for (int it = 0; it < 8; ++it){
    const int vl = sub + (it << 3);
    const int v = v0 + vl;
    if (v < 7000){
      // pass A: row max of s_k = th*be
      float m1 = -3.0e38f;
      #pragma unroll
      for (int k = 0; k < 50; ++k){
        float s = th[b][k]*be[k][vl];
        m1 = fmaxf(m1, s);
      }
      // pass B: e_k = exp(s_k - m1) (stored), S1
      float S1 = 0.f;
      #pragma unroll
      for (int k = 0; k < 50; ++k){
        float e = __expf(th[b][k]*be[k][vl] - m1);
        a[k] = e; S1 += e;
      }
      const float inv = 1.f/S1;
      // pass C: f_k = exp(pi_k) (overwrite a), F
      float F = 0.f;
      #pragma unroll
      for (int k = 0; k < 50; ++k){
        float fk = __expf(a[k]*inv);
        a[k] = fk; F += fk;
      }
      // inverse-CDF sample from softmax(pi)
      const unsigned int seed = (unsigned int)(((t*32) + b)*7000 + v);
      const float rthr = u01(seed) * F;
      float csum = 0.f; int ks = 49; bool found = false;
      #pragma unroll
      for (int k = 0; k < 50; ++k){
        csum += a[k];
        if (!found && csum >= rthr){ ks = k; found = true; }
      }
      // pi[ks] recomputed (1 exp)
      const float pis = __expf(th[b][ks]*be[ks][vl] - m1) * inv;
      const float lpis = __logf(pis);
      const float lt = lth[b][ks];
      if (v >= 5000){ kA2 += lt; kB2 += pis*lpis; }
      else          { kA1 += lt; kB1 += pis*lpis; }
      atomicAdd(&c0s[vl][ks], 1.f);
      atomicAdd(&c1s[(v >= 5000) ? 1 : 0][b][ks], 1.f);
    }
  }
  kA1 = wsum64(kA1); kB1 = wsum64(kB1); kA2 = wsum64(kA2); kB2 = wsum64(kB2);
  if ((tid & 63) == 0){
    atomicAdd(&kred[0], kA1); atomicAdd(&kred[1], kB1);
    atomicAdd(&kred[2], kA2); atomicAdd(&kred[3], kB2);
  }
  __syncthreads();
  for (int i = tid; i < 3200; i += 256){
    int vl = i / 50, k = i % 50, v = v0 + vl;
    if (v < 7000) c0g[((size_t)t*7000 + v)*50 + k] = c0s[vl][k];
  }
  for (int i = tid; i < 1600; i += 256){
    float x1 = ((float*)c1s)[i];
    float x2 = ((float*)c1s)[1600 + i];
    if (x1 != 0.f) atomicAdd(&c1g1[(size_t)t*1600 + i], x1);
    if (x2 != 0.f) atomicAdd(&c1g2[(size_t)t*1600 + i], x2);
  }
  if (tid < 4) atomicAdd(&accs[tid], kred[tid]);
}

// ---------------- pass2: log-likelihood ----------------
__global__ __launch_bounds__(256) void pass2(
    const float* __restrict__ beta, const float* __restrict__ theta,
    const float* __restrict__ c0g,
    const float* __restrict__ c1g1, const float* __restrict__ c1g2,
    const float* __restrict__ bows, float* __restrict__ accs)
{
  const int t = blockIdx.y, v0 = blockIdx.x * 64;
  __shared__ float be[50][64];
  __shared__ __align__(16) float tz[2][32][52];
  __shared__ __align__(16) float bz[64][52];
  __shared__ float sr[2];
  const int tid = threadIdx.x;
  if (tid < 2) sr[tid] = 0.f;
  for (int i = tid; i < 3200; i += 256){
    int k = i >> 6, vl = i & 63, v = v0 + vl;
    be[k][vl] = (v < 7000) ? beta[((size_t)t*50 + k)*7000 + v] : 0.f;
  }
  for (int i = tid; i < 1600; i += 256){
    int b = i / 50, k = i % 50;
    float th_ = theta[(size_t)t*1600 + i];
    tz[0][b][k] = th_ * c1g1[(size_t)t*1600 + i] * (1.f/5000.f);
    tz[1][b][k] = th_ * c1g2[(size_t)t*1600 + i] * (1.f/2000.f);
  }
  for (int i = tid; i < 128; i += 256){
    int b = i >> 2, rem = i & 3, p = rem >> 1, j = 50 + (rem & 1);
    tz[p][b][j] = 0.f;
  }
  __syncthreads();
  for (int i = tid; i < 3200; i += 256){
    int vl = i / 50, k = i % 50, v = v0 + vl;
    bz[vl][k] = (v < 7000) ? be[k][vl] * c0g[((size_t)t*7000 + v)*50 + k] * (1.f/32.f) : 0.f;
  }
  for (int i = tid; i < 128; i += 256){ int vl = i >> 1; bz[vl][50 + (i & 1)] = 0.f; }
  __syncthreads();

  const int b = tid >> 3, sub = tid & 7;
  float s1 = 0.f, s2 = 0.f;
  for (int it = 0; it < 8; ++it){
    const int vl = sub + (it << 3);
    const int v = v0 + vl;
    if (v < 7000){
      const int p = (v >= 5000);
      float dot = 0.f;
      #pragma unroll
      for (int kq = 0; kq < 13; ++kq){
        const float4 a = *(const float4*)&tz[p][b][kq << 2];
        const float4 c = *(const float4*)&bz[vl][kq << 2];
        dot += a.x*c.x + a.y*c.y + a.z*c.z + a.w*c.w;
      }
      const float w = bows[((size_t)b*12 + t)*7000 + v];
      const float l = __logf(dot) * w;
      if (p) s2 += l; else s1 += l;
    }
  }
  s1 = wsum64(s1); s2 = wsum64(s2);
  if ((tid & 63) == 0){ atomicAdd(&sr[0], s1); atomicAdd(&sr[1], s2); }
  __syncthreads();
  if (tid < 2) atomicAdd(&accs[4 + tid], sr[tid]);
}

// ---------------- finalize ----------------
__global__ void finalize_k(const float* __restrict__ accs, float* __restrict__ out){
  if (threadIdx.x == 0 && blockIdx.x == 0){
    out[0] = -(accs[4] + accs[5]) * (1.f/32.f);           // recon_loss = -ll1 - ll2
    out[1] = accs[6];                                     // kld_theta
    out[2] = -accs[0]/(32.f*5000.f) - accs[1]/32.f;       // kld_z1
    out[3] = -accs[2]/(32.f*2000.f) - accs[3]/32.f;       // kld_z2
    out[4] = accs[7];                                     // kld_alpha
  }
}

// ---------------- host launcher ----------------
extern "C" void kernel_launch(void* const* d_in, const int* in_sizes, int n_in,
                              void* d_out, int out_size, void* d_ws, size_t ws_size,
                              hipStream_t stream)
{
  const float* bows   = (const float*)d_in[0];
  const float* nbows  = (const float*)d_in[1];
  const float* qmap_w = (const float*)d_in[2];
  const float* qmap_b = (const float*)d_in[3];
  const float* wih0   = (const float*)d_in[4];
  const float* whh0   = (const float*)d_in[5];
  const float* bih0   = (const float*)d_in[6];
  const float* bhh0   = (const float*)d_in[7];
  const float* wih1   = (const float*)d_in[8];
  const float* whh1   = (const float*)d_in[9];
  const float* bih1   = (const float*)d_in[10];
  const float* bhh1   = (const float*)d_in[11];
  const float* muW    = (const float*)d_in[12];
  const float* muB    = (const float*)d_in[13];
  const float* lsW    = (const float*)d_in[14];
  const float* lsB    = (const float*)d_in[15];
  const float* qmu    = (const float*)d_in[16];
  const float* qlsa   = (const float*)d_in[17];
  const float* rho1w  = (const float*)d_in[18];
  const float* rho1b  = (const float*)d_in[19];
  const float* rho2w  = (const float*)d_in[20];
  const float* rho2b  = (const float*)d_in[21];

  float* ws  = (float*)d_ws;
  float* out = (float*)d_out;

  float* c1g1  = ws + OFF_C1G1;
  float* c1g2  = ws + OFF_C1G2;
  float* accs  = ws + OFF_ACCS;
  float* c0g   = ws + OFF_C0G;
  float* beta  = ws + OFF_BETA;
  float* alphT = ws + OFF_ALPHAT;
  float* inp   = ws + OFF_INP;
  float* X0    = ws + OFF_X0;
  float* out0  = ws + OFF_OUT0;
  float* X1    = ws + OFF_X1;
  float* out1  = ws + OFF_OUT1;
  float* cst   = ws + OFF_CST;
  float* muH   = ws + OFF_MUH;
  float* lsH   = ws + OFF_LSH;
  float* theta = ws + OFF_THETA;
  float* lth   = ws + OFF_LTH;
  float* muW4  = ws + OFF_MUW4;
  float* lsW4  = ws + OFF_LSW4;
  float* zsg   = ws + OFF_ZSG;

  // fused prep: zero accumulators + pack W450 + transpose alpha
  prep_misc<<<256, 256, 0, stream>>>(muW, lsW, qmu, c1g1, muW4, lsW4, alphT);
  kld_alpha_k<<<600, 64, 0, stream>>>(qmu, qlsa, accs);
  bias_all<<<2048, 256, 0, stream>>>(inp, X0, X1, muH, lsH,
                                     qmap_b, bih0, bhh0, bih1, bhh1, muB, lsB);

  // inp = nbows @ qmap_w^T + qmap_b   [384,400], K=7000
  gemm_f32<<<dim3(7,6,6), 256, 0, stream>>>(nbows, 7000, qmap_w, 7000, inp, 400,
                                            384, 400, 7000, 1168, nullptr, 0);

  // X0 = inp @ wih0^T + bih0 + bhh0   [384,1600], K=400
  gemm_f32<<<dim3(25,6,2), 256, 0, stream>>>(inp, 400, wih0, 400, X0, 1600,
                                             384, 1600, 400, 208, nullptr, 0);
  for (int t = 0; t < 12; ++t)
    lstm_step<<<100, 256, 0, stream>>>(X0, whh0, out0, cst, t);

  // X1 = out0 @ wih1^T + bih1 + bhh1
  gemm_f32<<<dim3(25,6,2), 256, 0, stream>>>(out0, 400, wih1, 400, X1, 1600,
                                             384, 1600, 400, 208, nullptr, 0);
  for (int t = 0; t < 12; ++t)
    lstm_step<<<100, 256, 0, stream>>>(X1, whh1, out1, cst, t);

  // muH/lsH = out1 @ W[:, :400]^T + b   [384,50], K=400
  gemm_f32<<<dim3(1,6,2), 256, 0, stream>>>(out1, 400, muW4, 400, muH, 50,
                                            384, 50, 400, 208, nullptr, 0);
  gemm_f32<<<dim3(1,6,2), 256, 0, stream>>>(out1, 400, lsW4, 400, lsH, 50,
                                            384, 50, 400, 208, nullptr, 0);

  theta_seq<<<1, 512, 0, stream>>>(muH, lsH, muW, lsW, theta, lth, zsg, accs);

  // beta logits (direct store + bias), then row-softmax per segment
  gemm_f32<<<dim3(79,10,1), 256, 0, stream>>>(alphT, 300, rho1w, 300, beta, 7000,
                                              600, 5000, 300, 300, rho1b, 1);
  gemm_f32<<<dim3(32,10,1), 256, 0, stream>>>(alphT, 300, rho2w, 300, beta + 5000, 7000,
                                              600, 2000, 300, 300, rho2b, 1);
  softmax_seg<<<dim3(600,2), 256, 0, stream>>>(beta);

  // likelihood
  pass1<<<dim3(110,12), 256, 0, stream>>>(beta, theta, lth, c0g, c1g1, c1g2, accs);
  pass2<<<dim3(110,12), 256, 0, stream>>>(beta, theta, c0g, c1g1, c1g2, bows, accs);

  finalize_k<<<1, 64, 0, stream>>>(accs, out);
}